// Round 2
// baseline (7622.438 us; speedup 1.0000x reference)
//
#include <hip/hip_runtime.h>
#include <stdint.h>

typedef __attribute__((ext_vector_type(4))) float f32x4;
typedef __attribute__((ext_vector_type(8))) short bf16x8;
typedef __attribute__((ext_vector_type(4))) unsigned int u32x4;
typedef __attribute__((ext_vector_type(2))) unsigned int u32x2;
typedef __attribute__((ext_vector_type(4))) unsigned short u16x4;
typedef unsigned short ushort_t;

#define B_N 32
#define T_N 1024
#define D_N 512
#define H_N 512
#define G4H 2048

__device__ __forceinline__ ushort_t f2bf(float f) {
    union { float f; unsigned int u; } v; v.f = f;
    unsigned int r = v.u + 0x7FFFu + ((v.u >> 16) & 1u);   // RNE
    return (ushort_t)(r >> 16);
}
__device__ __forceinline__ float bf2f(ushort_t b) {
    union { unsigned int u; float f; } v; v.u = ((unsigned int)b) << 16;
    return v.f;
}

// ---------------------------------------------------------------------------
// prep: fp32 -> bf16 conversion of x, W_ih, W_hh; bias_sum = b_ih+b_hh;
//       zero ring tags (must happen every launch: ws persists across graph
//       replays, and stale tags from a previous replay would look valid).
// ---------------------------------------------------------------------------
__global__ __launch_bounds__(256) void prep_kernel(
    const float* __restrict__ x, const float* __restrict__ wih,
    const float* __restrict__ whh, const float* __restrict__ bih,
    const float* __restrict__ bhh,
    ushort_t* __restrict__ xb, ushort_t* __restrict__ wihb,
    ushort_t* __restrict__ whhb, float* __restrict__ bias,
    unsigned int* __restrict__ ringu)
{
    size_t i = (size_t)blockIdx.x * 256 + threadIdx.x;
    if (i < 2048) bias[i] = bih[i] + bhh[i];
    if (i < 32768) ringu[i] = 0u;                    // invalid tag
    const size_t NX = (size_t)B_N * T_N * D_N / 4;   // 4194304 quads
    const size_t NW = (size_t)G4H * D_N / 4;         // 262144 quads
    if (i < NX) {
        f32x4 v = ((const f32x4*)x)[i];
        u16x4 o; o[0]=f2bf(v[0]); o[1]=f2bf(v[1]); o[2]=f2bf(v[2]); o[3]=f2bf(v[3]);
        ((u16x4*)xb)[i] = o;
    } else if (i < NX + NW) {
        size_t j = i - NX;
        f32x4 v = ((const f32x4*)wih)[j];
        u16x4 o; o[0]=f2bf(v[0]); o[1]=f2bf(v[1]); o[2]=f2bf(v[2]); o[3]=f2bf(v[3]);
        ((u16x4*)wihb)[j] = o;
    } else if (i < NX + 2 * NW) {
        size_t j = i - NX - NW;
        f32x4 v = ((const f32x4*)whh)[j];
        u16x4 o; o[0]=f2bf(v[0]); o[1]=f2bf(v[1]); o[2]=f2bf(v[2]); o[3]=f2bf(v[3]);
        ((u16x4*)whhb)[j] = o;
    }
}

// ---------------------------------------------------------------------------
// xg = x @ W_ih^T + (b_ih+b_hh), stored bf16 as [T][4H][B].
// ---------------------------------------------------------------------------
__global__ __launch_bounds__(512) void xg_gemm(
    const ushort_t* __restrict__ xb,    // [B][T][D] bf16
    const ushort_t* __restrict__ wihb,  // [4H][D] bf16
    const float* __restrict__ bias,     // [4H]
    ushort_t* __restrict__ xg)          // [T][4H][B] bf16
{
    int blk = blockIdx.x;
    int tc = blk >> 4;          // 0..127 (t-chunk of 8)
    int gb = blk & 15;          // 0..15  (gate-chunk of 128)
    int w  = threadIdx.x >> 6;  // wave 0..7
    int l  = threadIdx.x & 63;
    int lr = l & 15;
    int lk = l >> 4;

    int arow = gb * 128 + w * 16 + lr;                 // W_ih row (gate col)
    const ushort_t* ap = wihb + (size_t)arow * D_N;

    f32x4 acc[16];
#pragma unroll
    for (int i = 0; i < 16; ++i) { acc[i][0]=0.f; acc[i][1]=0.f; acc[i][2]=0.f; acc[i][3]=0.f; }

#pragma unroll
    for (int kk = 0; kk < 16; ++kk) {
        bf16x8 af = *(const bf16x8*)(ap + kk * 32 + lk * 8);
#pragma unroll
        for (int nn = 0; nn < 16; ++nn) {
            int tl = nn >> 1, bh = nn & 1;
            int bcol = bh * 16 + lr;
            int t = tc * 8 + tl;
            bf16x8 bf = *(const bf16x8*)(xb + ((size_t)bcol * T_N + t) * D_N + kk * 32 + lk * 8);
            acc[nn] = __builtin_amdgcn_mfma_f32_16x16x32_bf16(af, bf, acc[nn], 0, 0, 0);
        }
    }

    float bs[4];
#pragma unroll
    for (int j = 0; j < 4; ++j) bs[j] = bias[gb * 128 + w * 16 + lk * 4 + j];

#pragma unroll
    for (int nn = 0; nn < 16; ++nn) {
        int tl = nn >> 1, bh = nn & 1;
        int bcol = bh * 16 + lr;
        int t = tc * 8 + tl;
#pragma unroll
        for (int j = 0; j < 4; ++j) {
            int r = gb * 128 + w * 16 + lk * 4 + j;
            xg[((size_t)t * G4H + r) * B_N + bcol] = f2bf(acc[nn][j] + bs[j]);
        }
    }
}

// ---------------------------------------------------------------------------
// Sequential LSTM recurrence with self-validating tagged ring.
// 64 blocks x 256 threads. Block b: group g = b>>5 (batches 16g..16g+15),
// slice s = b&31 (h cols 16s..16s+15 -> gate cols {q*512+16s..}).
// Ring word = ((t+1)<<16) | bf16(h): data and freshness in one 32-bit store,
// so there is no counter, no store-ack wait, and no flag-ordering fence.
// Each wave polls its own A-fragments and proceeds independently (no
// pre-MFMA barrier); one __syncthreads per step for the LDS gate exchange
// (parity-buffered so no trailing barrier is needed).
// ---------------------------------------------------------------------------
__global__ __launch_bounds__(256, 1) void lstm_rec(
    const ushort_t* __restrict__ xg,    // [T][4H][B] bf16 (bias folded)
    const ushort_t* __restrict__ whhb,  // [4H][H] bf16
    unsigned int* __restrict__ ringu,   // [2 parity][2 group][16 batch][512 col] u32
    float* __restrict__ out,            // [B][T][H]
    float* __restrict__ hn,             // [B][H]
    float* __restrict__ cn)             // [B][H]
{
    const int tid = threadIdx.x;
    const int g = blockIdx.x >> 5;
    const int s = blockIdx.x & 31;
    const int w = tid >> 6, l = tid & 63, lr = l & 15, lk = l >> 4;

    __shared__ float glds[2][4][16][16];   // [parity][gate][batch][col]

    // ---- persistent W_hh fragments (B operand): lane lr -> gate col
    const int gc = w * 512 + s * 16 + lr;
    bf16x8 wfrag[16];
#pragma unroll
    for (int kk = 0; kk < 16; ++kk)
        wfrag[kk] = *(const bf16x8*)(whhb + (size_t)gc * H_N + kk * 32 + lk * 8);

    // ---- elementwise identity
    const int eb = tid >> 4;      // batch within group
    const int ej = tid & 15;      // col within slice
    float c_reg = 0.f;
    float* outp = out + ((size_t)(g * 16 + eb)) * T_N * H_N + s * 16 + ej;
    unsigned int* rp0 = ringu + g * 8192 + eb * 512 + s * 16 + ej;
    const ushort_t* xgp = xg + (size_t)gc * B_N + g * 16 + lk * 4;

    for (int t = 0; t < T_N; ++t) {
        // xg tile: issue before the poll; the poll's vmcnt(0) covers it
        u32x2 xv = *(const u32x2*)(xgp + (size_t)t * (G4H * B_N));

        f32x4 acc0, acc1;
        if (t > 0) {
            const unsigned int* hb = ringu + (((t - 1) & 1) * 2 + g) * 8192
                                     + lr * 512 + lk * 8;
            u32x4 af[32];
            const unsigned int tp = ((unsigned int)t) << 16;
            int ok, guard = 0;
            do {
                asm volatile(
                    "global_load_dwordx4 %0, %32, off sc0 sc1\n\t"
                    "global_load_dwordx4 %1, %32, off offset:16 sc0 sc1\n\t"
                    "global_load_dwordx4 %2, %32, off offset:128 sc0 sc1\n\t"
                    "global_load_dwordx4 %3, %32, off offset:144 sc0 sc1\n\t"
                    "global_load_dwordx4 %4, %32, off offset:256 sc0 sc1\n\t"
                    "global_load_dwordx4 %5, %32, off offset:272 sc0 sc1\n\t"
                    "global_load_dwordx4 %6, %32, off offset:384 sc0 sc1\n\t"
                    "global_load_dwordx4 %7, %32, off offset:400 sc0 sc1\n\t"
                    "global_load_dwordx4 %8, %32, off offset:512 sc0 sc1\n\t"
                    "global_load_dwordx4 %9, %32, off offset:528 sc0 sc1\n\t"
                    "global_load_dwordx4 %10, %32, off offset:640 sc0 sc1\n\t"
                    "global_load_dwordx4 %11, %32, off offset:656 sc0 sc1\n\t"
                    "global_load_dwordx4 %12, %32, off offset:768 sc0 sc1\n\t"
                    "global_load_dwordx4 %13, %32, off offset:784 sc0 sc1\n\t"
                    "global_load_dwordx4 %14, %32, off offset:896 sc0 sc1\n\t"
                    "global_load_dwordx4 %15, %32, off offset:912 sc0 sc1\n\t"
                    "global_load_dwordx4 %16, %32, off offset:1024 sc0 sc1\n\t"
                    "global_load_dwordx4 %17, %32, off offset:1040 sc0 sc1\n\t"
                    "global_load_dwordx4 %18, %32, off offset:1152 sc0 sc1\n\t"
                    "global_load_dwordx4 %19, %32, off offset:1168 sc0 sc1\n\t"
                    "global_load_dwordx4 %20, %32, off offset:1280 sc0 sc1\n\t"
                    "global_load_dwordx4 %21, %32, off offset:1296 sc0 sc1\n\t"
                    "global_load_dwordx4 %22, %32, off offset:1408 sc0 sc1\n\t"
                    "global_load_dwordx4 %23, %32, off offset:1424 sc0 sc1\n\t"
                    "global_load_dwordx4 %24, %32, off offset:1536 sc0 sc1\n\t"
                    "global_load_dwordx4 %25, %32, off offset:1552 sc0 sc1\n\t"
                    "global_load_dwordx4 %26, %32, off offset:1664 sc0 sc1\n\t"
                    "global_load_dwordx4 %27, %32, off offset:1680 sc0 sc1\n\t"
                    "global_load_dwordx4 %28, %32, off offset:1792 sc0 sc1\n\t"
                    "global_load_dwordx4 %29, %32, off offset:1808 sc0 sc1\n\t"
                    "global_load_dwordx4 %30, %32, off offset:1920 sc0 sc1\n\t"
                    "global_load_dwordx4 %31, %32, off offset:1936 sc0 sc1\n\t"
                    "s_waitcnt vmcnt(0)"
                    : "=&v"(af[0]), "=&v"(af[1]), "=&v"(af[2]), "=&v"(af[3]),
                      "=&v"(af[4]), "=&v"(af[5]), "=&v"(af[6]), "=&v"(af[7]),
                      "=&v"(af[8]), "=&v"(af[9]), "=&v"(af[10]), "=&v"(af[11]),
                      "=&v"(af[12]), "=&v"(af[13]), "=&v"(af[14]), "=&v"(af[15]),
                      "=&v"(af[16]), "=&v"(af[17]), "=&v"(af[18]), "=&v"(af[19]),
                      "=&v"(af[20]), "=&v"(af[21]), "=&v"(af[22]), "=&v"(af[23]),
                      "=&v"(af[24]), "=&v"(af[25]), "=&v"(af[26]), "=&v"(af[27]),
                      "=&v"(af[28]), "=&v"(af[29]), "=&v"(af[30]), "=&v"(af[31])
                    : "v"(hb)
                    : "memory");
                unsigned int d = 0;
#pragma unroll
                for (int j = 0; j < 32; ++j) {
                    d |= (af[j][0] ^ tp);
                    d |= (af[j][1] ^ tp);
                    d |= (af[j][2] ^ tp);
                    d |= (af[j][3] ^ tp);
                }
                ok = ((d & 0xFFFF0000u) == 0u);
            } while (!__all(ok) && ++guard < (1 << 16));

            // ---- acc init from xg (xv already in flight / complete)
            union { u32x2 u; ushort_t s4[4]; } xu; xu.u = xv;
#pragma unroll
            for (int j = 0; j < 4; ++j) { acc0[j] = bf2f(xu.s4[j]); acc1[j] = 0.f; }

            // ---- unpack tagged words -> bf16x8 A frags, MFMA (2 chains)
            union { u32x4 u; bf16x8 b; } up;
#pragma unroll
            for (int kk = 0; kk < 16; ++kk) {
                u32x4 w0 = af[2 * kk], w1 = af[2 * kk + 1];
                u32x4 p;
                p[0] = __builtin_amdgcn_perm(w0[1], w0[0], 0x05040100u);
                p[1] = __builtin_amdgcn_perm(w0[3], w0[2], 0x05040100u);
                p[2] = __builtin_amdgcn_perm(w1[1], w1[0], 0x05040100u);
                p[3] = __builtin_amdgcn_perm(w1[3], w1[2], 0x05040100u);
                up.u = p;
                if (kk & 1)
                    acc1 = __builtin_amdgcn_mfma_f32_16x16x32_bf16(up.b, wfrag[kk], acc1, 0, 0, 0);
                else
                    acc0 = __builtin_amdgcn_mfma_f32_16x16x32_bf16(up.b, wfrag[kk], acc0, 0, 0, 0);
            }
        } else {
            union { u32x2 u; ushort_t s4[4]; } xu; xu.u = xv;
#pragma unroll
            for (int j = 0; j < 4; ++j) { acc0[j] = bf2f(xu.s4[j]); acc1[j] = 0.f; }
        }

#pragma unroll
        for (int j = 0; j < 4; ++j) acc0[j] += acc1[j];

        // ---- gates to LDS (parity-buffered: one barrier per step)
#pragma unroll
        for (int j = 0; j < 4; ++j) glds[t & 1][w][lk * 4 + j][lr] = acc0[j];
        __syncthreads();

        // ---- elementwise LSTM cell
        float gi = glds[t & 1][0][eb][ej];
        float gf = glds[t & 1][1][eb][ej];
        float gg = glds[t & 1][2][eb][ej];
        float go = glds[t & 1][3][eb][ej];
        float i_ = 1.f / (1.f + __expf(-gi));
        float f_ = 1.f / (1.f + __expf(-gf));
        float g_ = tanhf(gg);
        float o_ = 1.f / (1.f + __expf(-go));
        c_reg = f_ * c_reg + i_ * g_;
        float hv = o_ * tanhf(c_reg);

        outp[(size_t)t * H_N] = hv;
        if (t == T_N - 1) {
            size_t bi = (size_t)(g * 16 + eb) * H_N + s * 16 + ej;
            hn[bi] = hv;
            cn[bi] = c_reg;
        }

        // ---- publish tagged h word (no ack wait, no flag, no atomic)
        unsigned int hw = (((unsigned int)(t + 1)) << 16) | (unsigned int)f2bf(hv);
        unsigned int* rp = rp0 + (t & 1) * 16384;
        asm volatile("global_store_dword %0, %1, off sc0 sc1"
                     :: "v"(rp), "v"(hw) : "memory");
    }
}

// ---------------------------------------------------------------------------
extern "C" void kernel_launch(void* const* d_in, const int* in_sizes, int n_in,
                              void* d_out, int out_size, void* d_ws, size_t ws_size,
                              hipStream_t stream) {
    (void)in_sizes; (void)n_in; (void)out_size; (void)ws_size;
    const float* x   = (const float*)d_in[0];
    const float* wih = (const float*)d_in[1];
    const float* whh = (const float*)d_in[2];
    const float* bih = (const float*)d_in[3];
    const float* bhh = (const float*)d_in[4];
    float* out = (float*)d_out;
    float* hn  = out + (size_t)B_N * T_N * H_N;
    float* cn  = hn + (size_t)B_N * H_N;

    char* ws = (char*)d_ws;
    // ws layout (all 256B-aligned):
    ushort_t*     xg    = (ushort_t*)    (ws);                  // 134217728 B
    ushort_t*     xb    = (ushort_t*)    (ws + 134217728);      //  33554432 B
    ushort_t*     wihb  = (ushort_t*)    (ws + 167772160);      //   2097152 B
    ushort_t*     whhb  = (ushort_t*)    (ws + 169869312);      //   2097152 B
    float*        bias  = (float*)       (ws + 171966464);      //      8192 B
    unsigned int* ringu = (unsigned int*)(ws + 171974656);      //    131072 B

    prep_kernel<<<18432, 256, 0, stream>>>(x, wih, whh, bih, bhh,
                                           xb, wihb, whhb, bias, ringu);
    xg_gemm<<<2048, 512, 0, stream>>>(xb, wihb, bias, xg);
    lstm_rec<<<64, 256, 0, stream>>>(xg, whhb, ringu, out, hn, cn);
}

// Round 4
// 4752.755 us; speedup vs baseline: 1.6038x; 1.6038x over previous
//
#include <hip/hip_runtime.h>
#include <stdint.h>

typedef __attribute__((ext_vector_type(4))) float f32x4;
typedef __attribute__((ext_vector_type(8))) short bf16x8;
typedef __attribute__((ext_vector_type(4))) unsigned int u32x4;
typedef __attribute__((ext_vector_type(2))) unsigned int u32x2;
typedef __attribute__((ext_vector_type(4))) unsigned short u16x4;
typedef unsigned short ushort_t;

#define B_N 32
#define T_N 1024
#define D_N 512
#define H_N 512
#define G4H 2048

__device__ __forceinline__ ushort_t f2bf(float f) {
    union { float f; unsigned int u; } v; v.f = f;
    unsigned int r = v.u + 0x7FFFu + ((v.u >> 16) & 1u);   // RNE
    return (ushort_t)(r >> 16);
}
__device__ __forceinline__ float bf2f(ushort_t b) {
    union { unsigned int u; float f; } v; v.u = ((unsigned int)b) << 16;
    return v.f;
}

// ---------------------------------------------------------------------------
// prep: fp32 -> bf16 conversion of x, W_ih, W_hh; bias_sum = b_ih+b_hh;
//       zero sentinel words (must happen every launch: ws persists across
//       graph replays; stale sentinels would pass the poll instantly).
//       The h-ring itself needs no reset: step 0 never reads it.
// ---------------------------------------------------------------------------
__global__ __launch_bounds__(256) void prep_kernel(
    const float* __restrict__ x, const float* __restrict__ wih,
    const float* __restrict__ whh, const float* __restrict__ bih,
    const float* __restrict__ bhh,
    ushort_t* __restrict__ xb, ushort_t* __restrict__ wihb,
    ushort_t* __restrict__ whhb, float* __restrict__ bias,
    unsigned int* __restrict__ sent)
{
    size_t i = (size_t)blockIdx.x * 256 + threadIdx.x;
    if (i < 2048) bias[i] = bih[i] + bhh[i];
    if (i < 512) sent[i] = 0u;
    const size_t NX = (size_t)B_N * T_N * D_N / 4;   // 4194304 quads
    const size_t NW = (size_t)G4H * D_N / 4;         // 262144 quads
    if (i < NX) {
        f32x4 v = ((const f32x4*)x)[i];
        u16x4 o; o[0]=f2bf(v[0]); o[1]=f2bf(v[1]); o[2]=f2bf(v[2]); o[3]=f2bf(v[3]);
        ((u16x4*)xb)[i] = o;
    } else if (i < NX + NW) {
        size_t j = i - NX;
        f32x4 v = ((const f32x4*)wih)[j];
        u16x4 o; o[0]=f2bf(v[0]); o[1]=f2bf(v[1]); o[2]=f2bf(v[2]); o[3]=f2bf(v[3]);
        ((u16x4*)wihb)[j] = o;
    } else if (i < NX + 2 * NW) {
        size_t j = i - NX - NW;
        f32x4 v = ((const f32x4*)whh)[j];
        u16x4 o; o[0]=f2bf(v[0]); o[1]=f2bf(v[1]); o[2]=f2bf(v[2]); o[3]=f2bf(v[3]);
        ((u16x4*)whhb)[j] = o;
    }
}

// ---------------------------------------------------------------------------
// xg = x @ W_ih^T + (b_ih+b_hh), stored bf16 as [T][4H][B].
// ---------------------------------------------------------------------------
__global__ __launch_bounds__(512) void xg_gemm(
    const ushort_t* __restrict__ xb,    // [B][T][D] bf16
    const ushort_t* __restrict__ wihb,  // [4H][D] bf16
    const float* __restrict__ bias,     // [4H]
    ushort_t* __restrict__ xg)          // [T][4H][B] bf16
{
    int blk = blockIdx.x;
    int tc = blk >> 4;          // 0..127 (t-chunk of 8)
    int gb = blk & 15;          // 0..15  (gate-chunk of 128)
    int w  = threadIdx.x >> 6;  // wave 0..7
    int l  = threadIdx.x & 63;
    int lr = l & 15;
    int lk = l >> 4;

    int arow = gb * 128 + w * 16 + lr;                 // W_ih row (gate col)
    const ushort_t* ap = wihb + (size_t)arow * D_N;

    f32x4 acc[16];
#pragma unroll
    for (int i = 0; i < 16; ++i) { acc[i][0]=0.f; acc[i][1]=0.f; acc[i][2]=0.f; acc[i][3]=0.f; }

#pragma unroll
    for (int kk = 0; kk < 16; ++kk) {
        bf16x8 af = *(const bf16x8*)(ap + kk * 32 + lk * 8);
#pragma unroll
        for (int nn = 0; nn < 16; ++nn) {
            int tl = nn >> 1, bh = nn & 1;
            int bcol = bh * 16 + lr;
            int t = tc * 8 + tl;
            bf16x8 bf = *(const bf16x8*)(xb + ((size_t)bcol * T_N + t) * D_N + kk * 32 + lk * 8);
            acc[nn] = __builtin_amdgcn_mfma_f32_16x16x32_bf16(af, bf, acc[nn], 0, 0, 0);
        }
    }

    float bs[4];
#pragma unroll
    for (int j = 0; j < 4; ++j) bs[j] = bias[gb * 128 + w * 16 + lk * 4 + j];

#pragma unroll
    for (int nn = 0; nn < 16; ++nn) {
        int tl = nn >> 1, bh = nn & 1;
        int bcol = bh * 16 + lr;
        int t = tc * 8 + tl;
#pragma unroll
        for (int j = 0; j < 4; ++j) {
            int r = gb * 128 + w * 16 + lk * 4 + j;
            xg[((size_t)t * G4H + r) * B_N + bcol] = f2bf(acc[nn][j] + bs[j]);
        }
    }
}

// ---------------------------------------------------------------------------
// Sequential LSTM recurrence, release/acquire sentinels.
// 64 blocks x 256 threads. Block b: group g = b>>5 (batches 16g..16g+15),
// slice s = b&31 (h cols 16s..16s+15 -> gate cols {q*512+16s..}).
// Producer wave: store h slice (bf16, sc0 sc1) -> s_waitcnt vmcnt(0)
// (release: stores acked at the device coherence point) -> lane0 stores
// sentinel word (t+1). Consumer wave: poll the group's 128 sentinels
// (one coalesced dwordx2 per lane, 512 B) until all >= t, then bulk-load
// h(t-1) once (16 KB, lands directly as MFMA A-fragments).
// Sentinel layout: [2 parity][2 group][32 slice][4 wave], parity stride 256
// words (BUG FIX vs prev round: producer used 512 -> OOB, parity-1 never
// signaled and the ring head was corrupted).
// ---------------------------------------------------------------------------
__global__ __launch_bounds__(256, 1) void lstm_rec(
    const ushort_t* __restrict__ xg,    // [T][4H][B] bf16 (bias folded)
    const ushort_t* __restrict__ whhb,  // [4H][H] bf16
    ushort_t* __restrict__ ringb,       // [2 parity][2 group][16 batch][512 col] bf16
    unsigned int* __restrict__ sent,    // [2 parity][2 group][32 slice][4 wave] u32
    float* __restrict__ out,            // [B][T][H]
    float* __restrict__ hn,             // [B][H]
    float* __restrict__ cn)             // [B][H]
{
    const int tid = threadIdx.x;
    const int g = blockIdx.x >> 5;
    const int s = blockIdx.x & 31;
    const int w = tid >> 6, l = tid & 63, lr = l & 15, lk = l >> 4;

    __shared__ float glds[2][4][16][16];   // [parity][gate][batch][col]

    // ---- persistent W_hh fragments (B operand): lane lr -> gate col
    const int gc = w * 512 + s * 16 + lr;
    bf16x8 wfrag[16];
#pragma unroll
    for (int kk = 0; kk < 16; ++kk)
        wfrag[kk] = *(const bf16x8*)(whhb + (size_t)gc * H_N + kk * 32 + lk * 8);

    // ---- elementwise identity
    const int eb = tid >> 4;      // batch within group
    const int ej = tid & 15;      // col within slice
    float c_reg = 0.f;
    float* outp = out + ((size_t)(g * 16 + eb)) * T_N * H_N + s * 16 + ej;
    ushort_t* rp0 = ringb + g * 8192 + eb * 512 + s * 16 + ej;     // + parity*16384
    unsigned int* sq0 = sent + g * 128 + s * 4 + w;                 // + parity*256
    const ushort_t* xgp = xg + (size_t)gc * B_N + g * 16 + lk * 4;

    for (int t = 0; t < T_N; ++t) {
        // xg tile: issue before the poll; covered by the poll's waitcnt
        u32x2 xv = *(const u32x2*)(xgp + (size_t)t * (G4H * B_N));

        f32x4 acc0, acc1;
        union { u32x2 u; ushort_t s4[4]; } xu; xu.u = xv;
#pragma unroll
        for (int j = 0; j < 4; ++j) { acc0[j] = bf2f(xu.s4[j]); acc1[j] = 0.f; }

        if (t > 0) {
            const int par = (t - 1) & 1;
            // ---- acquire: poll group's 128 sentinels (coalesced, 512 B)
            const unsigned int* spx = sent + par * 256 + g * 128 + l * 2;
            const unsigned int tgt = (unsigned int)t;
            int guard = 0;
            for (;;) {
                u32x2 sv;
                asm volatile("global_load_dwordx2 %0, %1, off sc0 sc1\n\t"
                             "s_waitcnt vmcnt(0)"
                             : "=&v"(sv) : "v"(spx) : "memory");
                int ok = (sv[0] >= tgt) && (sv[1] >= tgt);
                if (__all(ok) || ++guard > (1 << 18)) break;
            }

            // ---- bulk load h(t-1): 16 x dwordx4 = A-fragments directly
            const ushort_t* hb = ringb + (par * 2 + g) * 8192 + lr * 512 + lk * 8;
            u32x4 af[16];
            asm volatile(
                "global_load_dwordx4 %0, %16, off sc0 sc1\n\t"
                "global_load_dwordx4 %1, %16, off offset:64 sc0 sc1\n\t"
                "global_load_dwordx4 %2, %16, off offset:128 sc0 sc1\n\t"
                "global_load_dwordx4 %3, %16, off offset:192 sc0 sc1\n\t"
                "global_load_dwordx4 %4, %16, off offset:256 sc0 sc1\n\t"
                "global_load_dwordx4 %5, %16, off offset:320 sc0 sc1\n\t"
                "global_load_dwordx4 %6, %16, off offset:384 sc0 sc1\n\t"
                "global_load_dwordx4 %7, %16, off offset:448 sc0 sc1\n\t"
                "global_load_dwordx4 %8, %16, off offset:512 sc0 sc1\n\t"
                "global_load_dwordx4 %9, %16, off offset:576 sc0 sc1\n\t"
                "global_load_dwordx4 %10, %16, off offset:640 sc0 sc1\n\t"
                "global_load_dwordx4 %11, %16, off offset:704 sc0 sc1\n\t"
                "global_load_dwordx4 %12, %16, off offset:768 sc0 sc1\n\t"
                "global_load_dwordx4 %13, %16, off offset:832 sc0 sc1\n\t"
                "global_load_dwordx4 %14, %16, off offset:896 sc0 sc1\n\t"
                "global_load_dwordx4 %15, %16, off offset:960 sc0 sc1\n\t"
                "s_waitcnt vmcnt(0)"
                : "=&v"(af[0]), "=&v"(af[1]), "=&v"(af[2]), "=&v"(af[3]),
                  "=&v"(af[4]), "=&v"(af[5]), "=&v"(af[6]), "=&v"(af[7]),
                  "=&v"(af[8]), "=&v"(af[9]), "=&v"(af[10]), "=&v"(af[11]),
                  "=&v"(af[12]), "=&v"(af[13]), "=&v"(af[14]), "=&v"(af[15])
                : "v"(hb)
                : "memory");

            // ---- MFMA chain, 2 independent accumulators
            union { u32x4 u; bf16x8 b; } cv;
#pragma unroll
            for (int kk = 0; kk < 16; ++kk) {
                cv.u = af[kk];
                if (kk & 1)
                    acc1 = __builtin_amdgcn_mfma_f32_16x16x32_bf16(cv.b, wfrag[kk], acc1, 0, 0, 0);
                else
                    acc0 = __builtin_amdgcn_mfma_f32_16x16x32_bf16(cv.b, wfrag[kk], acc0, 0, 0, 0);
            }
        }

#pragma unroll
        for (int j = 0; j < 4; ++j) acc0[j] += acc1[j];

        // ---- gates to LDS (parity-buffered: one barrier per step)
#pragma unroll
        for (int j = 0; j < 4; ++j) glds[t & 1][w][lk * 4 + j][lr] = acc0[j];
        __syncthreads();

        // ---- elementwise LSTM cell
        float gi = glds[t & 1][0][eb][ej];
        float gf = glds[t & 1][1][eb][ej];
        float gg = glds[t & 1][2][eb][ej];
        float go = glds[t & 1][3][eb][ej];
        float i_ = 1.f / (1.f + __expf(-gi));
        float f_ = 1.f / (1.f + __expf(-gf));
        float g_ = tanhf(gg);
        float o_ = 1.f / (1.f + __expf(-go));
        c_reg = f_ * c_reg + i_ * g_;
        float hv = o_ * tanhf(c_reg);

        // ---- publish h slice (release part 1: the data stores)
        ushort_t* rp = rp0 + (t & 1) * 16384;
        unsigned int hbits = (unsigned int)f2bf(hv);
        asm volatile("global_store_short %0, %1, off sc0 sc1"
                     :: "v"(rp), "v"(hbits) : "memory");

        // ---- release part 2: wave-wide ack, then lane0 sentinel store
        asm volatile("s_waitcnt vmcnt(0)" ::: "memory");
        if (l == 0) {
            unsigned int* sq = sq0 + (t & 1) * 256;   // parity stride 256 words
            unsigned int tv = (unsigned int)(t + 1);
            asm volatile("global_store_dword %0, %1, off sc0 sc1"
                         :: "v"(sq), "v"(tv) : "memory");
        }

        // output write AFTER the sentinel: keeps its ack latency out of the
        // release critical path (drained by the next step's poll waitcnt)
        outp[(size_t)t * H_N] = hv;

        if (t == T_N - 1) {
            size_t bi = (size_t)(g * 16 + eb) * H_N + s * 16 + ej;
            hn[bi] = hv;
            cn[bi] = c_reg;
        }
    }
}

// ---------------------------------------------------------------------------
extern "C" void kernel_launch(void* const* d_in, const int* in_sizes, int n_in,
                              void* d_out, int out_size, void* d_ws, size_t ws_size,
                              hipStream_t stream) {
    (void)in_sizes; (void)n_in; (void)out_size; (void)ws_size;
    const float* x   = (const float*)d_in[0];
    const float* wih = (const float*)d_in[1];
    const float* whh = (const float*)d_in[2];
    const float* bih = (const float*)d_in[3];
    const float* bhh = (const float*)d_in[4];
    float* out = (float*)d_out;
    float* hn  = out + (size_t)B_N * T_N * H_N;
    float* cn  = hn + (size_t)B_N * H_N;

    char* ws = (char*)d_ws;
    // ws layout (all 256B-aligned):
    ushort_t*     xg    = (ushort_t*)    (ws);                  // 134217728 B
    ushort_t*     xb    = (ushort_t*)    (ws + 134217728);      //  33554432 B
    ushort_t*     wihb  = (ushort_t*)    (ws + 167772160);      //   2097152 B
    ushort_t*     whhb  = (ushort_t*)    (ws + 169869312);      //   2097152 B
    float*        bias  = (float*)       (ws + 171966464);      //      8192 B
    unsigned int* sent  = (unsigned int*)(ws + 171974656);      //      2048 B
    ushort_t*     ringb = (ushort_t*)    (ws + 171976704);      //     65536 B

    prep_kernel<<<18432, 256, 0, stream>>>(x, wih, whh, bih, bhh,
                                           xb, wihb, whhb, bias, sent);
    xg_gemm<<<2048, 512, 0, stream>>>(xb, wihb, bias, xg);
    lstm_rec<<<64, 256, 0, stream>>>(xg, whhb, ringb, sent, out, hn, cn);
}

// Round 6
// 3128.853 us; speedup vs baseline: 2.4362x; 1.5190x over previous
//
#include <hip/hip_runtime.h>
#include <stdint.h>

typedef __attribute__((ext_vector_type(4))) float f32x4;
typedef __attribute__((ext_vector_type(8))) short bf16x8;
typedef __attribute__((ext_vector_type(4))) unsigned int u32x4;
typedef __attribute__((ext_vector_type(2))) unsigned int u32x2;
typedef __attribute__((ext_vector_type(4))) unsigned short u16x4;
typedef unsigned short ushort_t;

#define B_N 32
#define T_N 1024
#define D_N 512
#define H_N 512
#define G4H 2048

__device__ __forceinline__ ushort_t f2bf(float f) {
    union { float f; unsigned int u; } v; v.f = f;
    unsigned int r = v.u + 0x7FFFu + ((v.u >> 16) & 1u);   // RNE
    return (ushort_t)(r >> 16);
}
__device__ __forceinline__ float bf2f(ushort_t b) {
    union { unsigned int u; float f; } v; v.u = ((unsigned int)b) << 16;
    return v.f;
}

// ---------------------------------------------------------------------------
// prep: fp32 -> bf16 of x, W_ih, W_hh; bias_sum = b_ih+b_hh; zero the tagged
// ring EVERY launch (ws persists across graph replays; stale tags from a
// previous replay would collide with step 1023's expected tag).
// ---------------------------------------------------------------------------
__global__ __launch_bounds__(256) void prep_kernel(
    const float* __restrict__ x, const float* __restrict__ wih,
    const float* __restrict__ whh, const float* __restrict__ bih,
    const float* __restrict__ bhh,
    ushort_t* __restrict__ xb, ushort_t* __restrict__ wihb,
    ushort_t* __restrict__ whhb, float* __restrict__ bias,
    unsigned int* __restrict__ ringu)
{
    size_t i = (size_t)blockIdx.x * 256 + threadIdx.x;
    if (i < 2048) bias[i] = bih[i] + bhh[i];
    if (i < 32768) ringu[i] = 0u;                    // tag 0 = never valid
    const size_t NX = (size_t)B_N * T_N * D_N / 4;   // 4194304 quads
    const size_t NW = (size_t)G4H * D_N / 4;         // 262144 quads
    if (i < NX) {
        f32x4 v = ((const f32x4*)x)[i];
        u16x4 o; o[0]=f2bf(v[0]); o[1]=f2bf(v[1]); o[2]=f2bf(v[2]); o[3]=f2bf(v[3]);
        ((u16x4*)xb)[i] = o;
    } else if (i < NX + NW) {
        size_t j = i - NX;
        f32x4 v = ((const f32x4*)wih)[j];
        u16x4 o; o[0]=f2bf(v[0]); o[1]=f2bf(v[1]); o[2]=f2bf(v[2]); o[3]=f2bf(v[3]);
        ((u16x4*)wihb)[j] = o;
    } else if (i < NX + 2 * NW) {
        size_t j = i - NX - NW;
        f32x4 v = ((const f32x4*)whh)[j];
        u16x4 o; o[0]=f2bf(v[0]); o[1]=f2bf(v[1]); o[2]=f2bf(v[2]); o[3]=f2bf(v[3]);
        ((u16x4*)whhb)[j] = o;
    }
}

// ---------------------------------------------------------------------------
// xg = x @ W_ih^T + (b_ih+b_hh), stored bf16 as [T][4H][B].
// ---------------------------------------------------------------------------
__global__ __launch_bounds__(512) void xg_gemm(
    const ushort_t* __restrict__ xb,    // [B][T][D] bf16
    const ushort_t* __restrict__ wihb,  // [4H][D] bf16
    const float* __restrict__ bias,     // [4H]
    ushort_t* __restrict__ xg)          // [T][4H][B] bf16
{
    int blk = blockIdx.x;
    int tc = blk >> 4;          // 0..127 (t-chunk of 8)
    int gb = blk & 15;          // 0..15  (gate-chunk of 128)
    int w  = threadIdx.x >> 6;  // wave 0..7
    int l  = threadIdx.x & 63;
    int lr = l & 15;
    int lk = l >> 4;

    int arow = gb * 128 + w * 16 + lr;                 // W_ih row (gate col)
    const ushort_t* ap = wihb + (size_t)arow * D_N;

    f32x4 acc[16];
#pragma unroll
    for (int i = 0; i < 16; ++i) { acc[i][0]=0.f; acc[i][1]=0.f; acc[i][2]=0.f; acc[i][3]=0.f; }

#pragma unroll
    for (int kk = 0; kk < 16; ++kk) {
        bf16x8 af = *(const bf16x8*)(ap + kk * 32 + lk * 8);
#pragma unroll
        for (int nn = 0; nn < 16; ++nn) {
            int tl = nn >> 1, bh = nn & 1;
            int bcol = bh * 16 + lr;
            int t = tc * 8 + tl;
            bf16x8 bf = *(const bf16x8*)(xb + ((size_t)bcol * T_N + t) * D_N + kk * 32 + lk * 8);
            acc[nn] = __builtin_amdgcn_mfma_f32_16x16x32_bf16(af, bf, acc[nn], 0, 0, 0);
        }
    }

    float bs[4];
#pragma unroll
    for (int j = 0; j < 4; ++j) bs[j] = bias[gb * 128 + w * 16 + lk * 4 + j];

#pragma unroll
    for (int nn = 0; nn < 16; ++nn) {
        int tl = nn >> 1, bh = nn & 1;
        int bcol = bh * 16 + lr;
        int t = tc * 8 + tl;
#pragma unroll
        for (int j = 0; j < 4; ++j) {
            int r = gb * 128 + w * 16 + lk * 4 + j;
            xg[((size_t)t * G4H + r) * B_N + bcol] = f2bf(acc[nn][j] + bs[j]);
        }
    }
}

// ---------------------------------------------------------------------------
// Sequential LSTM recurrence, tagged-data sync (no ack, no sentinel).
// 128 blocks x 512 threads. Block b: group g = b>>4 (batches 4g..4g+3),
// slice s = b&15 (h cols 32s..32s+31). Wave w: gate q=w&3, col-half w>>2.
// Ring word = ((t+1)<<16) | bf16(h): data + freshness in ONE 32-bit store;
// word-granular store atomicity makes each word self-validating, so the
// producer fires stores and moves on (no vmcnt ack, no flag ordering).
// One POLLER WAVE per block validates the group's h[4][512] (8 KB tagged,
// 8x dwordx4/lane, s_sleep(4) backoff) and stages packed bf16 into LDS;
// the other 7 waves consume via ds_read. 2-parity ring; clobber-safe:
// a producer entering step t+2 implies all blocks published h(t+1), which
// implies every poller finished reading h(t) (reads precede publishes).
// ---------------------------------------------------------------------------
__global__ __launch_bounds__(512, 1) void lstm_rec(
    const ushort_t* __restrict__ xg,    // [T][4H][B] bf16 (bias folded)
    const ushort_t* __restrict__ whhb,  // [4H][H] bf16
    unsigned int* __restrict__ ringu,   // [8 grp][2 par][4 batch][512 col] u32
    float* __restrict__ out,            // [B][T][H]
    float* __restrict__ hn,             // [B][H]
    float* __restrict__ cn)             // [B][H]
{
    const int tid = threadIdx.x;
    const int g = blockIdx.x >> 4;
    const int s = blockIdx.x & 15;
    const int w = tid >> 6, l = tid & 63, lr = l & 15, lk = l >> 4;

    __shared__ ushort_t hstage[4][520];   // packed h(t-1), +8 pad breaks bank alias
    __shared__ float glds[4][4][33];      // [gate][batch][col] (+1 pad)

    // ---- persistent W_hh fragments (B operand): lane lr -> gate col
    const int gc = (w & 3) * 512 + s * 32 + (w >> 2) * 16 + lr;
    bf16x8 wfrag[16];
#pragma unroll
    for (int kk = 0; kk < 16; ++kk)
        wfrag[kk] = *(const bf16x8*)(whhb + (size_t)gc * H_N + kk * 32 + lk * 8);

    // ---- elementwise identity (tid<128: 4 batches x 32 cols)
    const int eb = (tid >> 5) & 3;
    const int ej = tid & 31;
    const int bg = g * 4 + eb;
    float c_reg = 0.f;
    float* outp = out + (size_t)bg * T_N * H_N + s * 32 + ej;
    unsigned int* ringg = ringu + g * 4096;
    const ushort_t* xgp = xg + (size_t)gc * B_N + g * 4;

    for (int t = 0; t < T_N; ++t) {
        // xg tile (all lanes same addr -> broadcast; only rows 0-3 matter)
        u32x2 xv = *(const u32x2*)(xgp + (size_t)t * (G4H * B_N));
        f32x4 acc0, acc1;
        union { u32x2 u; ushort_t s4[4]; } xu; xu.u = xv;
#pragma unroll
        for (int j = 0; j < 4; ++j) { acc0[j] = bf2f(xu.s4[j]); acc1[j] = 0.f; }

        if (t > 0) {
            if (tid < 64) {
                // ---- poller wave: validate + stage h(t-1)
                const unsigned int* pp = ringg + ((t - 1) & 1) * 2048 + l * 32;
                const unsigned int tp = ((unsigned int)t) << 16;
                u32x4 a[8];
                int guard = 0;
                for (;;) {
                    asm volatile(
                        "global_load_dwordx4 %0, %8, off sc0 sc1\n\t"
                        "global_load_dwordx4 %1, %8, off offset:16 sc0 sc1\n\t"
                        "global_load_dwordx4 %2, %8, off offset:32 sc0 sc1\n\t"
                        "global_load_dwordx4 %3, %8, off offset:48 sc0 sc1\n\t"
                        "global_load_dwordx4 %4, %8, off offset:64 sc0 sc1\n\t"
                        "global_load_dwordx4 %5, %8, off offset:80 sc0 sc1\n\t"
                        "global_load_dwordx4 %6, %8, off offset:96 sc0 sc1\n\t"
                        "global_load_dwordx4 %7, %8, off offset:112 sc0 sc1\n\t"
                        "s_waitcnt vmcnt(0)"
                        : "=&v"(a[0]), "=&v"(a[1]), "=&v"(a[2]), "=&v"(a[3]),
                          "=&v"(a[4]), "=&v"(a[5]), "=&v"(a[6]), "=&v"(a[7])
                        : "v"(pp)
                        : "memory");
                    unsigned int d = 0;
#pragma unroll
                    for (int r = 0; r < 8; ++r) {
                        d |= (a[r][0] ^ tp); d |= (a[r][1] ^ tp);
                        d |= (a[r][2] ^ tp); d |= (a[r][3] ^ tp);
                    }
                    int ok = ((d & 0xFFFF0000u) == 0u);
                    if (__all(ok) || ++guard > (1 << 16)) break;
                    __builtin_amdgcn_s_sleep(4);   // backoff: caps poll traffic
                }
                // pack 32 tagged words -> 32 bf16 -> LDS (64 B contiguous)
                u32x4 p0, p1, p2, p3;
                p0[0] = __builtin_amdgcn_perm(a[0][1], a[0][0], 0x05040100u);
                p0[1] = __builtin_amdgcn_perm(a[0][3], a[0][2], 0x05040100u);
                p0[2] = __builtin_amdgcn_perm(a[1][1], a[1][0], 0x05040100u);
                p0[3] = __builtin_amdgcn_perm(a[1][3], a[1][2], 0x05040100u);
                p1[0] = __builtin_amdgcn_perm(a[2][1], a[2][0], 0x05040100u);
                p1[1] = __builtin_amdgcn_perm(a[2][3], a[2][2], 0x05040100u);
                p1[2] = __builtin_amdgcn_perm(a[3][1], a[3][0], 0x05040100u);
                p1[3] = __builtin_amdgcn_perm(a[3][3], a[3][2], 0x05040100u);
                p2[0] = __builtin_amdgcn_perm(a[4][1], a[4][0], 0x05040100u);
                p2[1] = __builtin_amdgcn_perm(a[4][3], a[4][2], 0x05040100u);
                p2[2] = __builtin_amdgcn_perm(a[5][1], a[5][0], 0x05040100u);
                p2[3] = __builtin_amdgcn_perm(a[5][3], a[5][2], 0x05040100u);
                p3[0] = __builtin_amdgcn_perm(a[6][1], a[6][0], 0x05040100u);
                p3[1] = __builtin_amdgcn_perm(a[6][3], a[6][2], 0x05040100u);
                p3[2] = __builtin_amdgcn_perm(a[7][1], a[7][0], 0x05040100u);
                p3[3] = __builtin_amdgcn_perm(a[7][3], a[7][2], 0x05040100u);
                char* base = (char*)hstage + (l >> 4) * 1040 + (l & 15) * 64;
                *(u32x4*)(base +  0) = p0;
                *(u32x4*)(base + 16) = p1;
                *(u32x4*)(base + 32) = p2;
                *(u32x4*)(base + 48) = p3;
            }
            __syncthreads();   // barrier 1: stage ready

            // ---- MFMA: A-frags from LDS (row = batch lr&3, replicated)
            const char* ap = (const char*)hstage + (lr & 3) * 1040 + lk * 16;
#pragma unroll
            for (int kk = 0; kk < 16; ++kk) {
                bf16x8 af = *(const bf16x8*)(ap + kk * 64);
                if (kk & 1)
                    acc1 = __builtin_amdgcn_mfma_f32_16x16x32_bf16(af, wfrag[kk], acc1, 0, 0, 0);
                else
                    acc0 = __builtin_amdgcn_mfma_f32_16x16x32_bf16(af, wfrag[kk], acc0, 0, 0, 0);
            }
        } else {
            __syncthreads();   // keep barrier structure uniform
        }

#pragma unroll
        for (int j = 0; j < 4; ++j) acc0[j] += acc1[j];

        // ---- gates to LDS (C rows 0-3 = batches, live in lk==0 lanes)
        if (lk == 0) {
#pragma unroll
            for (int j = 0; j < 4; ++j)
                glds[w & 3][j][(w >> 2) * 16 + lr] = acc0[j];
        }
        __syncthreads();   // barrier 2: gates ready

        // ---- elementwise cell + tagged publish (tid<128)
        if (tid < 128) {
            float gi = glds[0][eb][ej];
            float gf = glds[1][eb][ej];
            float gg = glds[2][eb][ej];
            float go = glds[3][eb][ej];
            float i_ = 1.f / (1.f + __expf(-gi));
            float f_ = 1.f / (1.f + __expf(-gf));
            float g_ = tanhf(gg);
            float o_ = 1.f / (1.f + __expf(-go));
            c_reg = f_ * c_reg + i_ * g_;
            float hv = o_ * tanhf(c_reg);

            // publish: ONE tagged store, fire-and-forget (no ack, no flag)
            unsigned int* rp = ringg + (t & 1) * 2048 + eb * 512 + s * 32 + ej;
            unsigned int hw = (((unsigned int)(t + 1)) << 16) | (unsigned int)f2bf(hv);
            asm volatile("global_store_dword %0, %1, off sc0 sc1"
                         :: "v"(rp), "v"(hw) : "memory");

            outp[(size_t)t * H_N] = hv;
            if (t == T_N - 1) {
                size_t bi = (size_t)bg * H_N + s * 32 + ej;
                hn[bi] = hv;
                cn[bi] = c_reg;
            }
        }
    }
}

// ---------------------------------------------------------------------------
extern "C" void kernel_launch(void* const* d_in, const int* in_sizes, int n_in,
                              void* d_out, int out_size, void* d_ws, size_t ws_size,
                              hipStream_t stream) {
    (void)in_sizes; (void)n_in; (void)out_size; (void)ws_size;
    const float* x   = (const float*)d_in[0];
    const float* wih = (const float*)d_in[1];
    const float* whh = (const float*)d_in[2];
    const float* bih = (const float*)d_in[3];
    const float* bhh = (const float*)d_in[4];
    float* out = (float*)d_out;
    float* hn  = out + (size_t)B_N * T_N * H_N;
    float* cn  = hn + (size_t)B_N * H_N;

    char* ws = (char*)d_ws;
    // ws layout (all 256B-aligned):
    ushort_t*     xg    = (ushort_t*)    (ws);                  // 134217728 B
    ushort_t*     xb    = (ushort_t*)    (ws + 134217728);      //  33554432 B
    ushort_t*     wihb  = (ushort_t*)    (ws + 167772160);      //   2097152 B
    ushort_t*     whhb  = (ushort_t*)    (ws + 169869312);      //   2097152 B
    float*        bias  = (float*)       (ws + 171966464);      //      8192 B
    unsigned int* ringu = (unsigned int*)(ws + 171974656);      //    131072 B

    prep_kernel<<<18432, 256, 0, stream>>>(x, wih, whh, bih, bhh,
                                           xb, wihb, whhb, bias, ringu);
    xg_gemm<<<2048, 512, 0, stream>>>(xb, wihb, bias, xg);
    lstm_rec<<<128, 512, 0, stream>>>(xg, whhb, ringu, out, hn, cn);
}

// Round 7
// 2672.996 us; speedup vs baseline: 2.8516x; 1.1705x over previous
//
#include <hip/hip_runtime.h>
#include <stdint.h>

typedef __attribute__((ext_vector_type(4))) float f32x4;
typedef __attribute__((ext_vector_type(8))) short bf16x8;
typedef __attribute__((ext_vector_type(4))) unsigned int u32x4;
typedef __attribute__((ext_vector_type(2))) unsigned int u32x2;
typedef __attribute__((ext_vector_type(4))) unsigned short u16x4;
typedef unsigned short ushort_t;

#define B_N 32
#define T_N 1024
#define D_N 512
#define H_N 512
#define G4H 2048

__device__ __forceinline__ ushort_t f2bf(float f) {
    union { float f; unsigned int u; } v; v.f = f;
    unsigned int r = v.u + 0x7FFFu + ((v.u >> 16) & 1u);   // RNE
    return (ushort_t)(r >> 16);
}
__device__ __forceinline__ float bf2f(ushort_t b) {
    union { unsigned int u; float f; } v; v.u = ((unsigned int)b) << 16;
    return v.f;
}
// fast sigmoid/tanh via v_exp_f32 + v_rcp_f32 (~1e-6 rel err << bf16 eps)
__device__ __forceinline__ float fsig(float x) {
    return __builtin_amdgcn_rcpf(1.f + __expf(-x));
}
__device__ __forceinline__ float ftanh(float x) {
    return 1.f - 2.f * __builtin_amdgcn_rcpf(1.f + __expf(2.f * x));
}

// ---------------------------------------------------------------------------
// prep: fp32 -> bf16 of x, W_ih, W_hh; bias_sum = b_ih+b_hh; zero the tagged
// ring EVERY launch (ws persists across graph replays; stale tags would
// collide with this run's expected tags).
// ---------------------------------------------------------------------------
__global__ __launch_bounds__(256) void prep_kernel(
    const float* __restrict__ x, const float* __restrict__ wih,
    const float* __restrict__ whh, const float* __restrict__ bih,
    const float* __restrict__ bhh,
    ushort_t* __restrict__ xb, ushort_t* __restrict__ wihb,
    ushort_t* __restrict__ whhb, float* __restrict__ bias,
    unsigned int* __restrict__ ringu)
{
    size_t i = (size_t)blockIdx.x * 256 + threadIdx.x;
    if (i < 2048) bias[i] = bih[i] + bhh[i];
    if (i < 32768) ringu[i] = 0u;                    // tag 0 = never valid
    const size_t NX = (size_t)B_N * T_N * D_N / 4;   // 4194304 quads
    const size_t NW = (size_t)G4H * D_N / 4;         // 262144 quads
    if (i < NX) {
        f32x4 v = ((const f32x4*)x)[i];
        u16x4 o; o[0]=f2bf(v[0]); o[1]=f2bf(v[1]); o[2]=f2bf(v[2]); o[3]=f2bf(v[3]);
        ((u16x4*)xb)[i] = o;
    } else if (i < NX + NW) {
        size_t j = i - NX;
        f32x4 v = ((const f32x4*)wih)[j];
        u16x4 o; o[0]=f2bf(v[0]); o[1]=f2bf(v[1]); o[2]=f2bf(v[2]); o[3]=f2bf(v[3]);
        ((u16x4*)wihb)[j] = o;
    } else if (i < NX + 2 * NW) {
        size_t j = i - NX - NW;
        f32x4 v = ((const f32x4*)whh)[j];
        u16x4 o; o[0]=f2bf(v[0]); o[1]=f2bf(v[1]); o[2]=f2bf(v[2]); o[3]=f2bf(v[3]);
        ((u16x4*)whhb)[j] = o;
    }
}

// ---------------------------------------------------------------------------
// xg = x @ W_ih^T + (b_ih+b_hh), stored bf16 as [T][4H][B].
// ---------------------------------------------------------------------------
__global__ __launch_bounds__(512) void xg_gemm(
    const ushort_t* __restrict__ xb,    // [B][T][D] bf16
    const ushort_t* __restrict__ wihb,  // [4H][D] bf16
    const float* __restrict__ bias,     // [4H]
    ushort_t* __restrict__ xg)          // [T][4H][B] bf16
{
    int blk = blockIdx.x;
    int tc = blk >> 4;          // 0..127 (t-chunk of 8)
    int gb = blk & 15;          // 0..15  (gate-chunk of 128)
    int w  = threadIdx.x >> 6;  // wave 0..7
    int l  = threadIdx.x & 63;
    int lr = l & 15;
    int lk = l >> 4;

    int arow = gb * 128 + w * 16 + lr;                 // W_ih row (gate col)
    const ushort_t* ap = wihb + (size_t)arow * D_N;

    f32x4 acc[16];
#pragma unroll
    for (int i = 0; i < 16; ++i) { acc[i][0]=0.f; acc[i][1]=0.f; acc[i][2]=0.f; acc[i][3]=0.f; }

#pragma unroll
    for (int kk = 0; kk < 16; ++kk) {
        bf16x8 af = *(const bf16x8*)(ap + kk * 32 + lk * 8);
#pragma unroll
        for (int nn = 0; nn < 16; ++nn) {
            int tl = nn >> 1, bh = nn & 1;
            int bcol = bh * 16 + lr;
            int t = tc * 8 + tl;
            bf16x8 bf = *(const bf16x8*)(xb + ((size_t)bcol * T_N + t) * D_N + kk * 32 + lk * 8);
            acc[nn] = __builtin_amdgcn_mfma_f32_16x16x32_bf16(af, bf, acc[nn], 0, 0, 0);
        }
    }

    float bs[4];
#pragma unroll
    for (int j = 0; j < 4; ++j) bs[j] = bias[gb * 128 + w * 16 + lk * 4 + j];

#pragma unroll
    for (int nn = 0; nn < 16; ++nn) {
        int tl = nn >> 1, bh = nn & 1;
        int bcol = bh * 16 + lr;
        int t = tc * 8 + tl;
#pragma unroll
        for (int j = 0; j < 4; ++j) {
            int r = gb * 128 + w * 16 + lk * 4 + j;
            xg[((size_t)t * G4H + r) * B_N + bcol] = f2bf(acc[nn][j] + bs[j]);
        }
    }
}

// ---------------------------------------------------------------------------
// Sequential LSTM recurrence, tagged-data sync + in-wave gate exchange.
// 128 blocks x 512 threads. Block b: group g = b>>4 (batches 4g..4g+3),
// slice s = b&15 (h cols 32s..32s+31). Wave w owns h-cols {s*32+w*4..+3}
// ACROSS ALL 4 GATES: B-frag lane map gc = (lr>>2)*512 + s*32 + w*4 +
// (lr&3), so after the MFMA the four gates of one (batch,col) live in
// lanes c, c+4, c+8, c+12 of the SAME wave -> 3 __shfl_xor replace the
// block-wide LDS gate exchange and its barrier.
// Ring word = ((t+1)<<16)|bf16(h): self-validating, fire-and-forget store.
// Poller wave (w==0) validates h[4][512] (8 KB tagged) and stages packed
// bf16 into LDS with wave-contiguous ds_write_b128 (row stride 544 -> 2-way
// bank aliasing = free); consumers ds_read A-frags after one barrier.
// Clobber-safe with parity-2 ring (producer t+2 implies all pollers read t).
// ---------------------------------------------------------------------------
__global__ __launch_bounds__(512, 1) void lstm_rec(
    const ushort_t* __restrict__ xg,    // [T][4H][B] bf16 (bias folded)
    const ushort_t* __restrict__ whhb,  // [4H][H] bf16
    unsigned int* __restrict__ ringu,   // [8 grp][2 par][4 batch][512 col] u32
    float* __restrict__ out,            // [B][T][H]
    float* __restrict__ hn,             // [B][H]
    float* __restrict__ cn)             // [B][H]
{
    const int tid = threadIdx.x;
    const int g = blockIdx.x >> 4;
    const int s = blockIdx.x & 15;
    const int w = tid >> 6, l = tid & 63, lr = l & 15, lk = l >> 4;

    __shared__ ushort_t hstage[4][544];   // packed h(t-1); 544: stride=16 banks

    // ---- persistent W_hh fragments (B operand): lane lr -> gate col
    const int col4 = s * 32 + w * 4;               // this wave's 4 h-cols
    const int gc = (lr >> 2) * 512 + col4 + (lr & 3);
    bf16x8 wfrag[16];
#pragma unroll
    for (int kk = 0; kk < 16; ++kk)
        wfrag[kk] = *(const bf16x8*)(whhb + (size_t)gc * H_N + kk * 32 + lk * 8);

    // ---- per-lane cell state: lanes 0-3 hold (col c = l, batches j=0..3)
    float c_reg[4] = {0.f, 0.f, 0.f, 0.f};
    unsigned int* ringg = ringu + g * 4096;
    const ushort_t* xgp = xg + (size_t)gc * B_N + g * 4;

    for (int t = 0; t < T_N; ++t) {
        // xg tile: batches 0-3 of this group (8 B broadcast across lk)
        u32x2 xv = *(const u32x2*)(xgp + (size_t)t * (G4H * B_N));
        f32x4 acc0, acc1;
        union { u32x2 u; ushort_t s4[4]; } xu; xu.u = xv;
#pragma unroll
        for (int j = 0; j < 4; ++j) { acc0[j] = bf2f(xu.s4[j]); acc1[j] = 0.f; }

        if (t > 0) {
            if (tid < 64) {
                // ---- poller wave: validate + stage h(t-1)
                // lane l loads rows 0-3, cols l*8..l*8+7 (write-contiguous map)
                const unsigned int* pp0 = ringg + ((t - 1) & 1) * 2048 + l * 8;
                const unsigned int* pp1 = pp0 + 1024;
                const unsigned int tp = ((unsigned int)t) << 16;
                u32x4 a[8];
                int guard = 0;
                for (;;) {
                    asm volatile(
                        "global_load_dwordx4 %0, %8, off sc0 sc1\n\t"
                        "global_load_dwordx4 %1, %8, off offset:16 sc0 sc1\n\t"
                        "global_load_dwordx4 %2, %8, off offset:2048 sc0 sc1\n\t"
                        "global_load_dwordx4 %3, %8, off offset:2064 sc0 sc1\n\t"
                        "global_load_dwordx4 %4, %9, off sc0 sc1\n\t"
                        "global_load_dwordx4 %5, %9, off offset:16 sc0 sc1\n\t"
                        "global_load_dwordx4 %6, %9, off offset:2048 sc0 sc1\n\t"
                        "global_load_dwordx4 %7, %9, off offset:2064 sc0 sc1\n\t"
                        "s_waitcnt vmcnt(0)"
                        : "=&v"(a[0]), "=&v"(a[1]), "=&v"(a[2]), "=&v"(a[3]),
                          "=&v"(a[4]), "=&v"(a[5]), "=&v"(a[6]), "=&v"(a[7])
                        : "v"(pp0), "v"(pp1)
                        : "memory");
                    unsigned int d = 0;
#pragma unroll
                    for (int r = 0; r < 8; ++r) {
                        d |= (a[r][0] ^ tp); d |= (a[r][1] ^ tp);
                        d |= (a[r][2] ^ tp); d |= (a[r][3] ^ tp);
                    }
                    int ok = ((d & 0xFFFF0000u) == 0u);
                    if (__all(ok) || ++guard > (1 << 16)) break;
                    __builtin_amdgcn_s_sleep(1);   // short backoff
                }
                // pack row n (2 dwordx4 -> 16 B) and write wave-contiguously:
                // ds_write_b128 #n covers row n, lane l at byte l*16.
#pragma unroll
                for (int n = 0; n < 4; ++n) {
                    u32x4 p;
                    p[0] = __builtin_amdgcn_perm(a[2*n][1], a[2*n][0], 0x05040100u);
                    p[1] = __builtin_amdgcn_perm(a[2*n][3], a[2*n][2], 0x05040100u);
                    p[2] = __builtin_amdgcn_perm(a[2*n+1][1], a[2*n+1][0], 0x05040100u);
                    p[3] = __builtin_amdgcn_perm(a[2*n+1][3], a[2*n+1][2], 0x05040100u);
                    *(u32x4*)((char*)hstage + n * 1088 + l * 16) = p;
                }
            }
            __syncthreads();   // barrier: stage ready (the only barrier/step)

            // ---- MFMA: A-frags from LDS (row = batch lr&3, replicated;
            //      row stride 1088 B == 16 banks -> 2-way alias, free)
            const char* ap = (const char*)hstage + (lr & 3) * 1088 + lk * 16;
#pragma unroll
            for (int kk = 0; kk < 16; ++kk) {
                bf16x8 af = *(const bf16x8*)(ap + kk * 64);
                if (kk & 1)
                    acc1 = __builtin_amdgcn_mfma_f32_16x16x32_bf16(af, wfrag[kk], acc1, 0, 0, 0);
                else
                    acc0 = __builtin_amdgcn_mfma_f32_16x16x32_bf16(af, wfrag[kk], acc0, 0, 0, 0);
            }
        } else {
            __syncthreads();   // uniform barrier structure
        }

#pragma unroll
        for (int j = 0; j < 4; ++j) acc0[j] += acc1[j];

        // ---- in-wave cell: activation per gate lane, then 3 shuffles
        // lane lr = q*4+c holds gate q of col c (rows/batches j in regs).
        const int q = (l >> 2) & 3;
        float av[4];
#pragma unroll
        for (int j = 0; j < 4; ++j)
            av[j] = (q == 2) ? ftanh(acc0[j]) : fsig(acc0[j]);

        float hv[4];
#pragma unroll
        for (int j = 0; j < 4; ++j) {
            float f_ = __shfl_xor(av[j], 4);
            float g_ = __shfl_xor(av[j], 8);
            float o_ = __shfl_xor(av[j], 12);
            // valid in lanes lr<4 (av[j] there = i-gate)
            c_reg[j] = f_ * c_reg[j] + av[j] * g_;
            hv[j] = o_ * ftanh(c_reg[j]);
        }

        // ---- publish + outputs (lanes 0-3 of every wave: col = col4 + l)
        if (l < 4) {
            unsigned int* rp = ringg + (t & 1) * 2048 + col4 + l;
            const unsigned int tag = ((unsigned int)(t + 1)) << 16;
#pragma unroll
            for (int j = 0; j < 4; ++j) {
                unsigned int hw = tag | (unsigned int)f2bf(hv[j]);
                asm volatile("global_store_dword %0, %1, off sc0 sc1"
                             :: "v"(rp + j * 512), "v"(hw) : "memory");
            }
            float* op = out + (size_t)(g * 4) * T_N * H_N + (size_t)t * H_N + col4 + l;
#pragma unroll
            for (int j = 0; j < 4; ++j)
                op[(size_t)j * T_N * H_N] = hv[j];
            if (t == T_N - 1) {
#pragma unroll
                for (int j = 0; j < 4; ++j) {
                    size_t bi = (size_t)(g * 4 + j) * H_N + col4 + l;
                    hn[bi] = hv[j];
                    cn[bi] = c_reg[j];
                }
            }
        }
    }
}

// ---------------------------------------------------------------------------
extern "C" void kernel_launch(void* const* d_in, const int* in_sizes, int n_in,
                              void* d_out, int out_size, void* d_ws, size_t ws_size,
                              hipStream_t stream) {
    (void)in_sizes; (void)n_in; (void)out_size; (void)ws_size;
    const float* x   = (const float*)d_in[0];
    const float* wih = (const float*)d_in[1];
    const float* whh = (const float*)d_in[2];
    const float* bih = (const float*)d_in[3];
    const float* bhh = (const float*)d_in[4];
    float* out = (float*)d_out;
    float* hn  = out + (size_t)B_N * T_N * H_N;
    float* cn  = hn + (size_t)B_N * H_N;

    char* ws = (char*)d_ws;
    // ws layout (all 256B-aligned):
    ushort_t*     xg    = (ushort_t*)    (ws);                  // 134217728 B
    ushort_t*     xb    = (ushort_t*)    (ws + 134217728);      //  33554432 B
    ushort_t*     wihb  = (ushort_t*)    (ws + 167772160);      //   2097152 B
    ushort_t*     whhb  = (ushort_t*)    (ws + 169869312);      //   2097152 B
    float*        bias  = (float*)       (ws + 171966464);      //      8192 B
    unsigned int* ringu = (unsigned int*)(ws + 171974656);      //    131072 B

    prep_kernel<<<18432, 256, 0, stream>>>(x, wih, whh, bih, bhh,
                                           xb, wihb, whhb, bias, ringu);
    xg_gemm<<<2048, 512, 0, stream>>>(xb, wihb, bias, xg);
    lstm_rec<<<128, 512, 0, stream>>>(xg, whhb, ringu, out, hn, cn);
}